// Round 7
// baseline (463.162 us; speedup 1.0000x reference)
//
#include <hip/hip_runtime.h>
#include <math.h>

// GCN 2-layer: out = Anorm( relu( Anorm(X W1) + b1 ) W2 ) + b2
// R14: NO global atomics. R9-R13 established a ~42us service-rate floor
//     (~14 atomics/ns) for returning device atomics that nothing moved.
//     Replace: 128 scan blocks each OWN a node range (<=1024 nodes, 4KB LDS
//     histogram). Each streams the whole dst[] (2.4MB, L2-resident per XCD)
//     and for in-range edges (1/128 of lanes) does an LDS atomicAdd (rank)
//     + fire-and-forget store eslot[d*CAP+rk]=src. Owner block then writes
//     counts+dinv for its range (k_dinv deleted).
//     Pipeline (4 dispatches): pre(weights) -> [scan || FULL gemm1] ->
//     aggemm -> agg2.

typedef __bf16 bf16x8 __attribute__((ext_vector_type(8)));
typedef float f32x4 __attribute__((ext_vector_type(4)));

constexpr int CAP = 32;      // slots per node; P(deg>=32 anywhere) ~ 1e-8
constexpr int NB_SCAN = 128; // scan blocks; per-block nodes <= 1024 (LDS)

union ABu {
  unsigned short u16[8];
  uint4 u4;
  bf16x8 v;
};

__device__ inline unsigned short f2bf(float f) {  // RNE
  unsigned u = __float_as_uint(f);
  return (unsigned short)((u + 0x7fffu + ((u >> 16) & 1u)) >> 16);
}

__device__ inline void unpack8(uint4 v, float* f) {
  f[0] = __uint_as_float(v.x << 16);
  f[1] = __uint_as_float(v.x & 0xffff0000u);
  f[2] = __uint_as_float(v.y << 16);
  f[3] = __uint_as_float(v.y & 0xffff0000u);
  f[4] = __uint_as_float(v.z << 16);
  f[5] = __uint_as_float(v.z & 0xffff0000u);
  f[6] = __uint_as_float(v.w << 16);
  f[7] = __uint_as_float(v.w & 0xffff0000u);
}

__device__ inline uint4 pack8(const float* a) {
  uint4 o;
  o.x = (unsigned)f2bf(a[0]) | ((unsigned)f2bf(a[1]) << 16);
  o.y = (unsigned)f2bf(a[2]) | ((unsigned)f2bf(a[3]) << 16);
  o.z = (unsigned)f2bf(a[4]) | ((unsigned)f2bf(a[5]) << 16);
  o.w = (unsigned)f2bf(a[6]) | ((unsigned)f2bf(a[7]) << 16);
  return o;
}

// ---------------- 1: convW only ----------------
__global__ __launch_bounds__(256) void k_pre(const float* __restrict__ W1,
                                             const float* __restrict__ W2,
                                             unsigned short* __restrict__ Wb1,
                                             unsigned short* __restrict__ Wb2) {
  int idx = blockIdx.x * 256 + threadIdx.x;
  if (idx < 128 * 128) {
    int k = idx >> 7, c = idx & 127;
    Wb1[(((k >> 3) << 7) + c) * 8 + (k & 7)] = f2bf(W1[idx]);
  } else {
    int j = idx - 128 * 128;
    int k = j >> 6, c = j & 63;
    Wb2[(((k >> 3) << 6) + c) * 8 + (k & 7)] = f2bf(W2[j]);
  }
}

// ---------------- device bodies ----------------

// scan: block owns node range [base, base+lim); streams all of dst;
// LDS-atomic rank + plain store for in-range edges; writes counts+dinv.
__device__ inline void scan_body(const int* __restrict__ src,
                                 const int* __restrict__ dst,
                                 int* __restrict__ counts,
                                 float* __restrict__ dinv,
                                 int* __restrict__ eslot,
                                 int E, int N, int bid, int* hist) {
  const int per = (N + NB_SCAN - 1) / NB_SCAN;  // 782 for N=100000
  const int base = bid * per;
  int lim = N - base;
  lim = lim < per ? lim : per;
  if (lim < 0) lim = 0;
  for (int i = threadIdx.x; i < lim; i += 256) hist[i] = 0;
  __syncthreads();

  const int4* d4 = (const int4*)dst;
  const int nv = E >> 2;
  for (int v = threadIdx.x; v < nv; v += 256) {
    int4 d = d4[v];
    int e0 = v << 2;
    unsigned r;
    r = (unsigned)(d.x - base);
    if (r < (unsigned)lim) {
      int rk = atomicAdd(&hist[r], 1);
      rk = rk < CAP - 1 ? rk : CAP - 1;
      eslot[(size_t)d.x * CAP + rk] = src[e0 + 0];
    }
    r = (unsigned)(d.y - base);
    if (r < (unsigned)lim) {
      int rk = atomicAdd(&hist[r], 1);
      rk = rk < CAP - 1 ? rk : CAP - 1;
      eslot[(size_t)d.y * CAP + rk] = src[e0 + 1];
    }
    r = (unsigned)(d.z - base);
    if (r < (unsigned)lim) {
      int rk = atomicAdd(&hist[r], 1);
      rk = rk < CAP - 1 ? rk : CAP - 1;
      eslot[(size_t)d.z * CAP + rk] = src[e0 + 2];
    }
    r = (unsigned)(d.w - base);
    if (r < (unsigned)lim) {
      int rk = atomicAdd(&hist[r], 1);
      rk = rk < CAP - 1 ? rk : CAP - 1;
      eslot[(size_t)d.w * CAP + rk] = src[e0 + 3];
    }
  }
  for (int e = (nv << 2) + (int)threadIdx.x; e < E; e += 256) {
    int dd = dst[e];
    unsigned r = (unsigned)(dd - base);
    if (r < (unsigned)lim) {
      int rk = atomicAdd(&hist[r], 1);
      rk = rk < CAP - 1 ? rk : CAP - 1;
      eslot[(size_t)dd * CAP + rk] = src[e];
    }
  }
  __syncthreads();
  for (int i = threadIdx.x; i < lim; i += 256) {
    int c = hist[i];
    counts[base + i] = c;
    dinv[base + i] = rsqrtf((float)(c + 1));
  }
}

// gemm1: h1[M,128](bf16) = X @ W1 (UNSCALED).
// A-frag: A[m=lane&15][k=(lane>>4)*8+j]; C/D: col=lane&15, row=(lane>>4)*4+reg
__device__ inline void gemm1_body(const float* __restrict__ X,
                                  const unsigned short* __restrict__ Wb,
                                  unsigned short* __restrict__ Cb, int M,
                                  int rowblk) {
  constexpr int K = 128, N = 128, NT = N / 16, KS = K / 32;
  const int tid = threadIdx.x;
  const int wave = tid >> 6;
  const int lane = tid & 63;
  const int q = lane >> 4;
  const int l15 = lane & 15;
  const int row0 = rowblk * 64 + wave * 16;
  const int rowA = row0 + l15;

  f32x4 zero = {0.0f, 0.0f, 0.0f, 0.0f};
  f32x4 acc[NT];
#pragma unroll
  for (int t = 0; t < NT; ++t) acc[t] = zero;

#pragma unroll
  for (int kk = 0; kk < KS; ++kk) {
    ABu a;
    float4 f0 = make_float4(0.f, 0.f, 0.f, 0.f);
    float4 f1 = make_float4(0.f, 0.f, 0.f, 0.f);
    if (rowA < M) {
      const float4* ap = (const float4*)(X + (size_t)rowA * K + kk * 32 + q * 8);
      f0 = ap[0];
      f1 = ap[1];
    }
    a.u16[0] = f2bf(f0.x); a.u16[1] = f2bf(f0.y);
    a.u16[2] = f2bf(f0.z); a.u16[3] = f2bf(f0.w);
    a.u16[4] = f2bf(f1.x); a.u16[5] = f2bf(f1.y);
    a.u16[6] = f2bf(f1.z); a.u16[7] = f2bf(f1.w);
#pragma unroll
    for (int nt = 0; nt < NT; ++nt) {
      ABu b;
      b.u4 = *(const uint4*)(Wb + ((size_t)(kk * 4 + q) * N + nt * 16 + l15) * 8);
      acc[nt] = __builtin_amdgcn_mfma_f32_16x16x32_bf16(a.v, b.v, acc[nt], 0, 0, 0);
    }
  }

#pragma unroll
  for (int v = 0; v < 4; ++v) {
    int row = row0 + q * 4 + v;
    if (row < M) {
#pragma unroll
      for (int nt = 0; nt < NT; ++nt)
        Cb[(size_t)row * N + nt * 16 + l15] = f2bf(acc[nt][v]);
    }
  }
}

// ---------------- 2: hybrid scan ∥ FULL gemm1 ----------------
__global__ __launch_bounds__(256) void k_scan_gemm1(
    const int* __restrict__ src, const int* __restrict__ dst,
    int* __restrict__ counts, float* __restrict__ dinv,
    int* __restrict__ eslot, int E, int N,
    const float* __restrict__ X, const unsigned short* __restrict__ Wb1,
    unsigned short* __restrict__ h1, int M) {
  __shared__ int hist[1024];  // >= ceil(N/NB_SCAN)
  if ((int)blockIdx.x < NB_SCAN)
    scan_body(src, dst, counts, dinv, eslot, E, N, blockIdx.x, hist);
  else
    gemm1_body(X, Wb1, h1, M, blockIdx.x - NB_SCAN);
}

// ---------------- 3: fused agg1 + GEMM2 ----------------
// inner = di*h1[node] + sum_e dinv[src]*h1[src]   (h1 UNSCALED)
// ag = bf16(relu(di*inner + b1)) -> LDS; h2s = (ag @ W2) * di (bf16)
// Gather: lane q loads sl[q] (coalesced line) + dinv[sl[q]]; idx/dv are
// shfl-broadcast across the 16-lane node-group.
__global__ __launch_bounds__(256) void k_aggemm(const unsigned short* __restrict__ h1,
                                                const float* __restrict__ dinv,
                                                const float* __restrict__ b1,
                                                const int* __restrict__ counts,
                                                const int* __restrict__ eslot,
                                                const unsigned short* __restrict__ Wb2,
                                                unsigned short* __restrict__ h2s,
                                                int n) {
  constexpr int LDA = 136;  // 128 + 8 pad, rows 16B-aligned
  __shared__ unsigned short As[16 * LDA];
  __shared__ float sdinv[16];
  const int tid = threadIdx.x;

  // phase 1: 16 nodes, 16 lanes each (8 ch/lane)
  {
    const int nl = tid >> 4;
    const int q = tid & 15;
    const int node = blockIdx.x * 16 + nl;
    float acc[8];
    if (node < n) {
      const uint4* h4 = (const uint4*)h1;
      float di = dinv[node];
      if (q == 0) sdinv[nl] = di;
      unpack8(h4[(size_t)node * 16 + q], acc);  // self (unscaled)
#pragma unroll
      for (int j = 0; j < 8; ++j) acc[j] *= di;  // di*h1[node]

      int cnt = counts[node];
      if (cnt > CAP) cnt = CAP;
      const int* sl = eslot + (size_t)node * CAP;
      if (cnt > 0) {
        // batch 0: slots [0,16)
        int lim = cnt < 16 ? cnt : 16;
        int my_s = sl[q < lim ? q : 0];   // coalesced 64B line per group
        float my_dv = dinv[my_s];         // one scattered 4B per lane
        for (int e = 0; e < lim; e += 8) {
          int idx[8];
          float dv[8];
#pragma unroll
          for (int i = 0; i < 8; ++i) {
            idx[i] = __shfl(my_s, e + i, 16);
            float dl = __shfl(my_dv, e + i, 16);
            dv[i] = (e + i < lim) ? dl : 0.f;
          }
          uint4 rr[8];
#pragma unroll
          for (int i = 0; i < 8; ++i) rr[i] = h4[(size_t)idx[i] * 16 + q];
#pragma unroll
          for (int i = 0; i < 8; ++i) {
            float g[8];
            unpack8(rr[i], g);
#pragma unroll
            for (int j = 0; j < 8; ++j) acc[j] = fmaf(g[j], dv[i], acc[j]);
          }
        }
        if (cnt > 16) {  // batch 1: slots [16,32) — rare (deg>16)
          int rem = cnt - 16;
          int my_s2 = sl[16 + (q < rem ? q : 0)];
          float my_dv2 = dinv[my_s2];
          for (int e = 0; e < rem; e += 8) {
            int idx[8];
            float dv[8];
#pragma unroll
            for (int i = 0; i < 8; ++i) {
              idx[i] = __shfl(my_s2, e + i, 16);
              float dl = __shfl(my_dv2, e + i, 16);
              dv[i] = (e + i < rem) ? dl : 0.f;
            }
            uint4 rr[8];
#pragma unroll
            for (int i = 0; i < 8; ++i) rr[i] = h4[(size_t)idx[i] * 16 + q];
#pragma unroll
            for (int i = 0; i < 8; ++i) {
              float g[8];
              unpack8(rr[i], g);
#pragma unroll
              for (int j = 0; j < 8; ++j) acc[j] = fmaf(g[j], dv[i], acc[j]);
            }
          }
        }
      }
      const float4* b14 = (const float4*)b1;
      float4 ba = b14[q * 2], bb = b14[q * 2 + 1];
      float bias[8] = {ba.x, ba.y, ba.z, ba.w, bb.x, bb.y, bb.z, bb.w};
#pragma unroll
      for (int i = 0; i < 8; ++i) acc[i] = fmaxf(fmaf(acc[i], di, bias[i]), 0.f);
    } else {
      if (q == 0) sdinv[nl] = 0.f;
#pragma unroll
      for (int i = 0; i < 8; ++i) acc[i] = 0.f;
    }
    *(uint4*)&As[nl * LDA + q * 8] = pack8(acc);
  }
  __syncthreads();

  // phase 2: one wave per 16-col tile; 4 MFMAs each; h2s pre-scaled by dinv
  {
    const int wave = tid >> 6;
    const int lane = tid & 63;
    const int q = lane >> 4;
    const int l15 = lane & 15;
    f32x4 acc = {0.0f, 0.0f, 0.0f, 0.0f};
#pragma unroll
    for (int kk = 0; kk < 4; ++kk) {
      ABu a, b;
      a.u4 = *(const uint4*)&As[l15 * LDA + kk * 32 + q * 8];
      b.u4 = *(const uint4*)(Wb2 + ((size_t)(kk * 4 + q) * 64 + wave * 16 + l15) * 8);
      acc = __builtin_amdgcn_mfma_f32_16x16x32_bf16(a.v, b.v, acc, 0, 0, 0);
    }
#pragma unroll
    for (int v = 0; v < 4; ++v) {
      int rl = q * 4 + v;
      int row = blockIdx.x * 16 + rl;
      if (row < n) h2s[(size_t)row * 64 + wave * 16 + l15] = f2bf(acc[v] * sdinv[rl]);
    }
  }
}

// ---------------- 4: agg2 ----------------
// out[node,:] = di*(h2s[node] + sum h2s[src]) + b2 (h2s pre-scaled; fp32 out)
// Gather: 8 lanes/node; per 8-slot batch lane q loads sl[b*8+q]; shfl width 8.
__global__ __launch_bounds__(256) void k_agg2(const unsigned short* __restrict__ h2s,
                                              const float* __restrict__ dinv,
                                              const float* __restrict__ b2,
                                              const int* __restrict__ counts,
                                              const int* __restrict__ eslot,
                                              float* __restrict__ out, int n) {
  constexpr int CQ = 8;  // 64 ch / 8 per lane
  const int tid = threadIdx.x;
  const int node = blockIdx.x * 32 + tid / CQ;
  const int q = tid % CQ;
  if (node >= n) return;

  const uint4* h4 = (const uint4*)h2s;
  float di = dinv[node];
  float acc[8];
  unpack8(h4[(size_t)node * CQ + q], acc);

  int cnt = counts[node];
  if (cnt > CAP) cnt = CAP;
  const int* sl = eslot + (size_t)node * CAP;
  for (int b = 0; b * 8 < cnt; ++b) {
    int rem = cnt - b * 8;          // >0
    int lim = rem < 8 ? rem : 8;
    int my_s = sl[b * 8 + (q < lim ? q : 0)];
    int idx[8];
#pragma unroll
    for (int i = 0; i < 8; ++i) idx[i] = __shfl(my_s, i, 8);
    uint4 rr[8];
#pragma unroll
    for (int i = 0; i < 8; ++i) rr[i] = h4[(size_t)idx[i] * CQ + q];
#pragma unroll
    for (int i = 0; i < 8; ++i) {
      float w = (i < lim) ? 1.f : 0.f;
      float g[8];
      unpack8(rr[i], g);
#pragma unroll
      for (int j = 0; j < 8; ++j) acc[j] = fmaf(g[j], w, acc[j]);
    }
  }

  const float4* b24 = (const float4*)b2;
  float4 ba = b24[q * 2], bb = b24[q * 2 + 1];
  float bias[8] = {ba.x, ba.y, ba.z, ba.w, bb.x, bb.y, bb.z, bb.w};
  float4 o0, o1;
  o0.x = fmaf(acc[0], di, bias[0]);
  o0.y = fmaf(acc[1], di, bias[1]);
  o0.z = fmaf(acc[2], di, bias[2]);
  o0.w = fmaf(acc[3], di, bias[3]);
  o1.x = fmaf(acc[4], di, bias[4]);
  o1.y = fmaf(acc[5], di, bias[5]);
  o1.z = fmaf(acc[6], di, bias[6]);
  o1.w = fmaf(acc[7], di, bias[7]);
  ((float4*)out)[(size_t)node * 16 + q * 2 + 0] = o0;
  ((float4*)out)[(size_t)node * 16 + q * 2 + 1] = o1;
}

// ---------------- launch ----------------

extern "C" void kernel_launch(void* const* d_in, const int* in_sizes, int n_in,
                              void* d_out, int out_size, void* d_ws, size_t ws_size,
                              hipStream_t stream) {
  const float* x  = (const float*)d_in[0];
  const float* W1 = (const float*)d_in[1];
  const float* b1 = (const float*)d_in[2];
  const float* W2 = (const float*)d_in[3];
  const float* b2 = (const float*)d_in[4];
  const int* src  = (const int*)d_in[5];
  const int* dst  = (const int*)d_in[6];
  float* out = (float*)d_out;

  constexpr int IN_C = 128, HID_C = 128, OUT_C = 64;
  const int N = in_sizes[0] / IN_C;   // 100000
  const int E = in_sizes[5];          // 600000

  char* p = (char*)d_ws;
  auto alloc = [&](size_t bytes) {
    char* r = p;
    p += (bytes + 255) & ~(size_t)255;
    return r;
  };
  float* dinv    = (float*)alloc((size_t)N * 4);
  int*   counts  = (int*)alloc((size_t)N * 4);
  int*   eslot   = (int*)alloc((size_t)N * CAP * 4);
  unsigned short* Wb1 = (unsigned short*)alloc((size_t)IN_C * HID_C * 2);
  unsigned short* Wb2 = (unsigned short*)alloc((size_t)HID_C * OUT_C * 2);
  unsigned short* h1  = (unsigned short*)alloc((size_t)N * HID_C * 2);
  unsigned short* h2s = (unsigned short*)alloc((size_t)N * OUT_C * 2);

  const int T = 256;
  const int RB_TOTAL = (N + 63) / 64;          // 1563 gemm1 row-blocks
  constexpr int CONV_BLOCKS = (128 * 128 + 128 * 64) / 256;  // 96

  k_pre<<<CONV_BLOCKS, T, 0, stream>>>(W1, W2, Wb1, Wb2);
  k_scan_gemm1<<<NB_SCAN + RB_TOTAL, T, 0, stream>>>(src, dst, counts, dinv, eslot,
                                                     E, N, x, Wb1, h1, N);
  k_aggemm<<<(N + 15) / 16, T, 0, stream>>>(h1, dinv, b1, counts, eslot, Wb2, h2s, N);
  k_agg2<<<(N + 31) / 32, T, 0, stream>>>(h2s, dinv, b2, counts, eslot, out, N);
}

// Round 8
// 188.336 us; speedup vs baseline: 2.4592x; 2.4592x over previous
//
#include <hip/hip_runtime.h>
#include <math.h>

// GCN 2-layer: out = Anorm( relu( Anorm(X W1) + b1 ) W2 ) + b2
// R15: two-pass radix binning kills the 42us atomic floor without R14's
//     redundant-stream latency disaster.
//     Pass A (293 blocks, hybrid w/ FULL gemm1): LDS-count 2048 edges into
//       98 bins (bin = dst>>10), ONE global returning atomic per bin per
//       block reserves space (28.7K atomics ~3us vs 600K ~42us), scatter
//       (src,dst) int2 into binBuf.
//     Pass B (98 blocks): each reads only its bin (~6K edges, coalesced),
//       LDS-histogram exact ranks, writes eslot + counts + dinv.
//     aggemm/agg2 unchanged from R13 (+ stale-slot index clamps).

typedef __bf16 bf16x8 __attribute__((ext_vector_type(8)));
typedef float f32x4 __attribute__((ext_vector_type(4)));

constexpr int CAP = 32;     // slots per node; P(deg>=32 anywhere) ~ 1e-8
constexpr int CAPB = 8192;  // per-bin capacity; mean 6144, +26 sigma

union ABu {
  unsigned short u16[8];
  uint4 u4;
  bf16x8 v;
};

__device__ inline unsigned short f2bf(float f) {  // RNE
  unsigned u = __float_as_uint(f);
  return (unsigned short)((u + 0x7fffu + ((u >> 16) & 1u)) >> 16);
}

__device__ inline void unpack8(uint4 v, float* f) {
  f[0] = __uint_as_float(v.x << 16);
  f[1] = __uint_as_float(v.x & 0xffff0000u);
  f[2] = __uint_as_float(v.y << 16);
  f[3] = __uint_as_float(v.y & 0xffff0000u);
  f[4] = __uint_as_float(v.z << 16);
  f[5] = __uint_as_float(v.z & 0xffff0000u);
  f[6] = __uint_as_float(v.w << 16);
  f[7] = __uint_as_float(v.w & 0xffff0000u);
}

__device__ inline uint4 pack8(const float* a) {
  uint4 o;
  o.x = (unsigned)f2bf(a[0]) | ((unsigned)f2bf(a[1]) << 16);
  o.y = (unsigned)f2bf(a[2]) | ((unsigned)f2bf(a[3]) << 16);
  o.z = (unsigned)f2bf(a[4]) | ((unsigned)f2bf(a[5]) << 16);
  o.w = (unsigned)f2bf(a[6]) | ((unsigned)f2bf(a[7]) << 16);
  return o;
}

// ---------------- 1: convW ∪ zero bin cursors ----------------
__global__ __launch_bounds__(256) void k_pre(const float* __restrict__ W1,
                                             const float* __restrict__ W2,
                                             unsigned short* __restrict__ Wb1,
                                             unsigned short* __restrict__ Wb2,
                                             int* __restrict__ gCur, int nbins) {
  constexpr int CONV_BLOCKS = (128 * 128 + 128 * 64) / 256;  // 96
  if (blockIdx.x == CONV_BLOCKS) {
    if ((int)threadIdx.x < nbins) gCur[threadIdx.x] = 0;
    return;
  }
  int idx = blockIdx.x * 256 + threadIdx.x;
  if (idx < 128 * 128) {
    int k = idx >> 7, c = idx & 127;
    Wb1[(((k >> 3) << 7) + c) * 8 + (k & 7)] = f2bf(W1[idx]);
  } else {
    int j = idx - 128 * 128;
    int k = j >> 6, c = j & 63;
    Wb2[(((k >> 3) << 6) + c) * 8 + (k & 7)] = f2bf(W2[j]);
  }
}

// ---------------- device bodies ----------------

// pass A: 8 edges/thread; LDS bin counts; 1 cursor atomic per bin per block;
// scatter (src,dst) into per-bin buffer regions.
__device__ inline void binA_body(const int* __restrict__ src,
                                 const int* __restrict__ dst,
                                 int* __restrict__ gCur,
                                 int2* __restrict__ binBuf,
                                 int E, int nbins, int bid,
                                 int* bc, int* bbase) {
  const int tid = threadIdx.x;
  if (tid < 128) bc[tid] = 0;
  __syncthreads();
  int base = (bid * 256 + tid) * 8;
  int ds[8], ss[8];
  bool vl[8];
  if (base + 7 < E) {
    int4 d0 = *(const int4*)(dst + base);
    int4 d1 = *(const int4*)(dst + base + 4);
    int4 s0 = *(const int4*)(src + base);
    int4 s1 = *(const int4*)(src + base + 4);
    ds[0] = d0.x; ds[1] = d0.y; ds[2] = d0.z; ds[3] = d0.w;
    ds[4] = d1.x; ds[5] = d1.y; ds[6] = d1.z; ds[7] = d1.w;
    ss[0] = s0.x; ss[1] = s0.y; ss[2] = s0.z; ss[3] = s0.w;
    ss[4] = s1.x; ss[5] = s1.y; ss[6] = s1.z; ss[7] = s1.w;
#pragma unroll
    for (int i = 0; i < 8; ++i) vl[i] = true;
  } else {
#pragma unroll
    for (int i = 0; i < 8; ++i) {
      int e = base + i;
      bool v = e < E;
      int ee = v ? e : E - 1;
      ds[i] = dst[ee]; ss[i] = src[ee]; vl[i] = v;
    }
  }
#pragma unroll
  for (int i = 0; i < 8; ++i)
    if (vl[i]) atomicAdd(&bc[ds[i] >> 10], 1);
  __syncthreads();
  if (tid < nbins) bbase[tid] = atomicAdd(&gCur[tid], bc[tid]);
  __syncthreads();
  if (tid < 128) bc[tid] = 0;
  __syncthreads();
#pragma unroll
  for (int i = 0; i < 8; ++i) {
    if (vl[i]) {
      int b = ds[i] >> 10;
      int pos = bbase[b] + atomicAdd(&bc[b], 1);
      if (pos < CAPB) binBuf[(size_t)b * CAPB + pos] = make_int2(ss[i], ds[i]);
    }
  }
}

// gemm1: h1[M,128](bf16) = X @ W1 (UNSCALED).
// A-frag: A[m=lane&15][k=(lane>>4)*8+j]; C/D: col=lane&15, row=(lane>>4)*4+reg
__device__ inline void gemm1_body(const float* __restrict__ X,
                                  const unsigned short* __restrict__ Wb,
                                  unsigned short* __restrict__ Cb, int M,
                                  int rowblk) {
  constexpr int K = 128, N = 128, NT = N / 16, KS = K / 32;
  const int tid = threadIdx.x;
  const int wave = tid >> 6;
  const int lane = tid & 63;
  const int q = lane >> 4;
  const int l15 = lane & 15;
  const int row0 = rowblk * 64 + wave * 16;
  const int rowA = row0 + l15;

  f32x4 zero = {0.0f, 0.0f, 0.0f, 0.0f};
  f32x4 acc[NT];
#pragma unroll
  for (int t = 0; t < NT; ++t) acc[t] = zero;

#pragma unroll
  for (int kk = 0; kk < KS; ++kk) {
    ABu a;
    float4 f0 = make_float4(0.f, 0.f, 0.f, 0.f);
    float4 f1 = make_float4(0.f, 0.f, 0.f, 0.f);
    if (rowA < M) {
      const float4* ap = (const float4*)(X + (size_t)rowA * K + kk * 32 + q * 8);
      f0 = ap[0];
      f1 = ap[1];
    }
    a.u16[0] = f2bf(f0.x); a.u16[1] = f2bf(f0.y);
    a.u16[2] = f2bf(f0.z); a.u16[3] = f2bf(f0.w);
    a.u16[4] = f2bf(f1.x); a.u16[5] = f2bf(f1.y);
    a.u16[6] = f2bf(f1.z); a.u16[7] = f2bf(f1.w);
#pragma unroll
    for (int nt = 0; nt < NT; ++nt) {
      ABu b;
      b.u4 = *(const uint4*)(Wb + ((size_t)(kk * 4 + q) * N + nt * 16 + l15) * 8);
      acc[nt] = __builtin_amdgcn_mfma_f32_16x16x32_bf16(a.v, b.v, acc[nt], 0, 0, 0);
    }
  }

#pragma unroll
  for (int v = 0; v < 4; ++v) {
    int row = row0 + q * 4 + v;
    if (row < M) {
#pragma unroll
      for (int nt = 0; nt < NT; ++nt)
        Cb[(size_t)row * N + nt * 16 + l15] = f2bf(acc[nt][v]);
    }
  }
}

// ---------------- 2: hybrid pass A ∥ FULL gemm1 ----------------
__global__ __launch_bounds__(256) void k_binA_gemm1(
    const int* __restrict__ src, const int* __restrict__ dst,
    int* __restrict__ gCur, int2* __restrict__ binBuf, int E, int nbins,
    int EB, const float* __restrict__ X, const unsigned short* __restrict__ Wb1,
    unsigned short* __restrict__ h1, int M) {
  __shared__ int bc[128];
  __shared__ int bbase[128];
  if ((int)blockIdx.x < EB)
    binA_body(src, dst, gCur, binBuf, E, nbins, blockIdx.x, bc, bbase);
  else
    gemm1_body(X, Wb1, h1, M, blockIdx.x - EB);
}

// ---------------- 3: pass B — per-bin rank build + counts + dinv ----------
__global__ __launch_bounds__(256) void k_binB(const int2* __restrict__ binBuf,
                                              const int* __restrict__ gCur,
                                              int* __restrict__ counts,
                                              float* __restrict__ dinv,
                                              int* __restrict__ eslot, int N) {
  __shared__ int hist[1024];
  const int b = blockIdx.x;
  const int base = b << 10;
  int lim = N - base;
  lim = lim < 1024 ? lim : 1024;
  for (int i = threadIdx.x; i < 1024; i += 256) hist[i] = 0;
  __syncthreads();
  int cnt = gCur[b];
  cnt = cnt < CAPB ? cnt : CAPB;
  const int2* bb = binBuf + (size_t)b * CAPB;
  for (int i = threadIdx.x; i < cnt; i += 256) {
    int2 pr = bb[i];
    int rk = atomicAdd(&hist[pr.y - base], 1);
    rk = rk < CAP - 1 ? rk : CAP - 1;
    eslot[(size_t)pr.y * CAP + rk] = pr.x;
  }
  __syncthreads();
  for (int i = threadIdx.x; i < lim; i += 256) {
    int c = hist[i];
    counts[base + i] = c;
    dinv[base + i] = rsqrtf((float)(c + 1));
  }
}

// ---------------- 4: fused agg1 + GEMM2 ----------------
// inner = di*h1[node] + sum_e dinv[src]*h1[src]   (h1 UNSCALED)
// ag = bf16(relu(di*inner + b1)) -> LDS; h2s = (ag @ W2) * di (bf16)
__global__ __launch_bounds__(256) void k_aggemm(const unsigned short* __restrict__ h1,
                                                const float* __restrict__ dinv,
                                                const float* __restrict__ b1,
                                                const int* __restrict__ counts,
                                                const int* __restrict__ eslot,
                                                const unsigned short* __restrict__ Wb2,
                                                unsigned short* __restrict__ h2s,
                                                int n) {
  constexpr int LDA = 136;  // 128 + 8 pad, rows 16B-aligned
  __shared__ unsigned short As[16 * LDA];
  __shared__ float sdinv[16];
  const int tid = threadIdx.x;

  // phase 1: 16 nodes, 16 lanes each (8 ch/lane)
  {
    const int nl = tid >> 4;
    const int q = tid & 15;
    const int node = blockIdx.x * 16 + nl;
    float acc[8];
    if (node < n) {
      const uint4* h4 = (const uint4*)h1;
      float di = dinv[node];
      if (q == 0) sdinv[nl] = di;
      unpack8(h4[(size_t)node * 16 + q], acc);  // self (unscaled)
#pragma unroll
      for (int j = 0; j < 8; ++j) acc[j] *= di;  // di*h1[node]

      int cnt = counts[node];
      if (cnt > CAP) cnt = CAP;
      const int* sl = eslot + (size_t)node * CAP;
      if (cnt > 0) {
        // batch 0: slots [0,16)
        int lim = cnt < 16 ? cnt : 16;
        int my_s = sl[q < lim ? q : 0];   // coalesced 64B line per group
        if ((unsigned)my_s >= (unsigned)n) my_s = 0;  // stale-slot guard
        float my_dv = dinv[my_s];         // one scattered 4B per lane
        for (int e = 0; e < lim; e += 8) {
          int idx[8];
          float dv[8];
#pragma unroll
          for (int i = 0; i < 8; ++i) {
            idx[i] = __shfl(my_s, e + i, 16);
            float dl = __shfl(my_dv, e + i, 16);
            dv[i] = (e + i < lim) ? dl : 0.f;
          }
          uint4 rr[8];
#pragma unroll
          for (int i = 0; i < 8; ++i) rr[i] = h4[(size_t)idx[i] * 16 + q];
#pragma unroll
          for (int i = 0; i < 8; ++i) {
            float g[8];
            unpack8(rr[i], g);
#pragma unroll
            for (int j = 0; j < 8; ++j) acc[j] = fmaf(g[j], dv[i], acc[j]);
          }
        }
        if (cnt > 16) {  // batch 1: slots [16,32) — rare (deg>16)
          int rem = cnt - 16;
          int my_s2 = sl[16 + (q < rem ? q : 0)];
          if ((unsigned)my_s2 >= (unsigned)n) my_s2 = 0;
          float my_dv2 = dinv[my_s2];
          for (int e = 0; e < rem; e += 8) {
            int idx[8];
            float dv[8];
#pragma unroll
            for (int i = 0; i < 8; ++i) {
              idx[i] = __shfl(my_s2, e + i, 16);
              float dl = __shfl(my_dv2, e + i, 16);
              dv[i] = (e + i < rem) ? dl : 0.f;
            }
            uint4 rr[8];
#pragma unroll
            for (int i = 0; i < 8; ++i) rr[i] = h4[(size_t)idx[i] * 16 + q];
#pragma unroll
            for (int i = 0; i < 8; ++i) {
              float g[8];
              unpack8(rr[i], g);
#pragma unroll
              for (int j = 0; j < 8; ++j) acc[j] = fmaf(g[j], dv[i], acc[j]);
            }
          }
        }
      }
      const float4* b14 = (const float4*)b1;
      float4 ba = b14[q * 2], bb = b14[q * 2 + 1];
      float bias[8] = {ba.x, ba.y, ba.z, ba.w, bb.x, bb.y, bb.z, bb.w};
#pragma unroll
      for (int i = 0; i < 8; ++i) acc[i] = fmaxf(fmaf(acc[i], di, bias[i]), 0.f);
    } else {
      if (q == 0) sdinv[nl] = 0.f;
#pragma unroll
      for (int i = 0; i < 8; ++i) acc[i] = 0.f;
    }
    *(uint4*)&As[nl * LDA + q * 8] = pack8(acc);
  }
  __syncthreads();

  // phase 2: one wave per 16-col tile; 4 MFMAs each; h2s pre-scaled by dinv
  {
    const int wave = tid >> 6;
    const int lane = tid & 63;
    const int q = lane >> 4;
    const int l15 = lane & 15;
    f32x4 acc = {0.0f, 0.0f, 0.0f, 0.0f};
#pragma unroll
    for (int kk = 0; kk < 4; ++kk) {
      ABu a, b;
      a.u4 = *(const uint4*)&As[l15 * LDA + kk * 32 + q * 8];
      b.u4 = *(const uint4*)(Wb2 + ((size_t)(kk * 4 + q) * 64 + wave * 16 + l15) * 8);
      acc = __builtin_amdgcn_mfma_f32_16x16x32_bf16(a.v, b.v, acc, 0, 0, 0);
    }
#pragma unroll
    for (int v = 0; v < 4; ++v) {
      int rl = q * 4 + v;
      int row = blockIdx.x * 16 + rl;
      if (row < n) h2s[(size_t)row * 64 + wave * 16 + l15] = f2bf(acc[v] * sdinv[rl]);
    }
  }
}

// ---------------- 5: agg2 ----------------
// out[node,:] = di*(h2s[node] + sum h2s[src]) + b2 (h2s pre-scaled; fp32 out)
__global__ __launch_bounds__(256) void k_agg2(const unsigned short* __restrict__ h2s,
                                              const float* __restrict__ dinv,
                                              const float* __restrict__ b2,
                                              const int* __restrict__ counts,
                                              const int* __restrict__ eslot,
                                              float* __restrict__ out, int n) {
  constexpr int CQ = 8;  // 64 ch / 8 per lane
  const int tid = threadIdx.x;
  const int node = blockIdx.x * 32 + tid / CQ;
  const int q = tid % CQ;
  if (node >= n) return;

  const uint4* h4 = (const uint4*)h2s;
  float di = dinv[node];
  float acc[8];
  unpack8(h4[(size_t)node * CQ + q], acc);

  int cnt = counts[node];
  if (cnt > CAP) cnt = CAP;
  const int* sl = eslot + (size_t)node * CAP;
  for (int b = 0; b * 8 < cnt; ++b) {
    int rem = cnt - b * 8;          // >0
    int lim = rem < 8 ? rem : 8;
    int my_s = sl[b * 8 + (q < lim ? q : 0)];
    if ((unsigned)my_s >= (unsigned)n) my_s = 0;  // stale-slot guard
    int idx[8];
#pragma unroll
    for (int i = 0; i < 8; ++i) idx[i] = __shfl(my_s, i, 8);
    uint4 rr[8];
#pragma unroll
    for (int i = 0; i < 8; ++i) rr[i] = h4[(size_t)idx[i] * CQ + q];
#pragma unroll
    for (int i = 0; i < 8; ++i) {
      float w = (i < lim) ? 1.f : 0.f;
      float g[8];
      unpack8(rr[i], g);
#pragma unroll
      for (int j = 0; j < 8; ++j) acc[j] = fmaf(g[j], w, acc[j]);
    }
  }

  const float4* b24 = (const float4*)b2;
  float4 ba = b24[q * 2], bb = b24[q * 2 + 1];
  float bias[8] = {ba.x, ba.y, ba.z, ba.w, bb.x, bb.y, bb.z, bb.w};
  float4 o0, o1;
  o0.x = fmaf(acc[0], di, bias[0]);
  o0.y = fmaf(acc[1], di, bias[1]);
  o0.z = fmaf(acc[2], di, bias[2]);
  o0.w = fmaf(acc[3], di, bias[3]);
  o1.x = fmaf(acc[4], di, bias[4]);
  o1.y = fmaf(acc[5], di, bias[5]);
  o1.z = fmaf(acc[6], di, bias[6]);
  o1.w = fmaf(acc[7], di, bias[7]);
  ((float4*)out)[(size_t)node * 16 + q * 2 + 0] = o0;
  ((float4*)out)[(size_t)node * 16 + q * 2 + 1] = o1;
}

// ---------------- launch ----------------

extern "C" void kernel_launch(void* const* d_in, const int* in_sizes, int n_in,
                              void* d_out, int out_size, void* d_ws, size_t ws_size,
                              hipStream_t stream) {
  const float* x  = (const float*)d_in[0];
  const float* W1 = (const float*)d_in[1];
  const float* b1 = (const float*)d_in[2];
  const float* W2 = (const float*)d_in[3];
  const float* b2 = (const float*)d_in[4];
  const int* src  = (const int*)d_in[5];
  const int* dst  = (const int*)d_in[6];
  float* out = (float*)d_out;

  constexpr int IN_C = 128, HID_C = 128, OUT_C = 64;
  const int N = in_sizes[0] / IN_C;   // 100000
  const int E = in_sizes[5];          // 600000
  const int nbins = (N + 1023) >> 10; // 98 (<=128 required)

  char* p = (char*)d_ws;
  auto alloc = [&](size_t bytes) {
    char* r = p;
    p += (bytes + 255) & ~(size_t)255;
    return r;
  };
  int*   gCur    = (int*)alloc((size_t)nbins * 4);
  int2*  binBuf  = (int2*)alloc((size_t)nbins * CAPB * 8);   // 6.4 MB
  float* dinv    = (float*)alloc((size_t)N * 4);
  int*   counts  = (int*)alloc((size_t)N * 4);
  int*   eslot   = (int*)alloc((size_t)N * CAP * 4);         // 12.8 MB
  unsigned short* Wb1 = (unsigned short*)alloc((size_t)IN_C * HID_C * 2);
  unsigned short* Wb2 = (unsigned short*)alloc((size_t)HID_C * OUT_C * 2);
  unsigned short* h1  = (unsigned short*)alloc((size_t)N * HID_C * 2);
  unsigned short* h2s = (unsigned short*)alloc((size_t)N * OUT_C * 2);

  const int T = 256;
  const int EB8 = ((E + 7) / 8 + T - 1) / T;   // 293 pass-A blocks
  const int RB_TOTAL = (N + 63) / 64;          // 1563 gemm1 row-blocks
  constexpr int CONV_BLOCKS = (128 * 128 + 128 * 64) / 256;  // 96

  k_pre<<<CONV_BLOCKS + 1, T, 0, stream>>>(W1, W2, Wb1, Wb2, gCur, nbins);
  k_binA_gemm1<<<EB8 + RB_TOTAL, T, 0, stream>>>(src, dst, gCur, binBuf, E, nbins,
                                                 EB8, x, Wb1, h1, N);
  k_binB<<<nbins, T, 0, stream>>>(binBuf, gCur, counts, dinv, eslot, N);
  k_aggemm<<<(N + 15) / 16, T, 0, stream>>>(h1, dinv, b1, counts, eslot, Wb2, h2s, N);
  k_agg2<<<(N + 31) / 32, T, 0, stream>>>(h2s, dinv, b2, counts, eslot, out, N);
}